// Round 1
// baseline (23.352 us; speedup 1.0000x reference)
//
#include <hip/hip_runtime.h>
#include <math.h>

#define NTHREADS 256
#define CHUNK 8
#define T_DIM 2048
#define B_DIM 1024

// One block per batch row. Each thread owns CHUNK=8 consecutive timesteps.
// Two fused (predicted,true) float2 block scans: theta (exclusive), x (inclusive).
__global__ __launch_bounds__(NTHREADS) void path_loss_rows(
    const float* __restrict__ outs,
    const int*   __restrict__ labels,
    float*       __restrict__ partial)
{
  __shared__ float2 sbuf[NTHREADS];
  __shared__ float  rbuf[NTHREADS];

  const int tid = threadIdx.x;
  const int b   = blockIdx.x;
  const int t0  = tid * CHUNK;

  const float* rowO = outs   + (size_t)b * T_DIM * 5;
  const int*   rowL = labels + (size_t)b * T_DIM;

  // ---- load 8 timesteps x 5 classes = 40 floats, 16B-aligned (tid*160B) ----
  float vals[40];
  const float4* vp = reinterpret_cast<const float4*>(rowO + (size_t)t0 * 5);
  #pragma unroll
  for (int j = 0; j < 10; ++j) {
    float4 v = vp[j];
    vals[4*j+0] = v.x; vals[4*j+1] = v.y; vals[4*j+2] = v.z; vals[4*j+3] = v.w;
  }
  // ---- 8 int32 labels = 32B, 16B-aligned ----
  int lbl[CHUNK];
  const int4* lp = reinterpret_cast<const int4*>(rowL + t0);
  {
    int4 l0 = lp[0], l1 = lp[1];
    lbl[0]=l0.x; lbl[1]=l0.y; lbl[2]=l0.z; lbl[3]=l0.w;
    lbl[4]=l1.x; lbl[5]=l1.y; lbl[6]=l1.z; lbl[7]=l1.w;
  }

  const float WT = 1.0f / (1.0f + 1e-6f);
  float dthP[CHUNK], fwP[CHUNK], dthT[CHUNK], fwT[CHUNK];
  #pragma unroll
  for (int k = 0; k < CHUNK; ++k) {
    float o0 = vals[5*k+0], o1 = vals[5*k+1], o2 = vals[5*k+2],
          o3 = vals[5*k+3], o4 = vals[5*k+4];
    // first-occurrence argmax (strict >) matches jnp.argmax
    float m = o0; int am = 0;
    if (o1 > m) { m = o1; am = 1; }
    if (o2 > m) { m = o2; am = 2; }
    if (o3 > m) { m = o3; am = 3; }
    if (o4 > m) { m = o4; am = 4; }
    float sum = __expf(o0-m) + __expf(o1-m) + __expf(o2-m)
              + __expf(o3-m) + __expf(o4-m);
    float s = 1.0f / sum;            // softmax value at argmax
    float w = s / (s + 1e-6f);
    float sgn = (am==1 || am==3) ? 1.0f : ((am==2 || am==4) ? -1.0f : 0.0f);
    fwP[k]  = (am==0 || am==3 || am==4) ? w : 0.0f;
    dthP[k] = 0.15f * sgn * w;

    int l = lbl[k];
    float sgt = (l==1 || l==3) ? 1.0f : ((l==2 || l==4) ? -1.0f : 0.0f);
    fwT[k]  = (l==0 || l==3 || l==4) ? WT : 0.0f;
    dthT[k] = 0.15f * sgt * WT;
  }

  // ---- scan 1: theta = exclusive prefix of dth (fused P/T in float2) ----
  float2 csum = make_float2(0.f, 0.f);
  #pragma unroll
  for (int k = 0; k < CHUNK; ++k) { csum.x += dthP[k]; csum.y += dthT[k]; }

  sbuf[tid] = csum;
  __syncthreads();
  #pragma unroll
  for (int off = 1; off < NTHREADS; off <<= 1) {
    float2 a = make_float2(0.f, 0.f);
    if (tid >= off) a = sbuf[tid - off];
    __syncthreads();
    if (tid >= off) { float2 c = sbuf[tid]; c.x += a.x; c.y += a.y; sbuf[tid] = c; }
    __syncthreads();
  }
  float2 thBase = (tid > 0) ? sbuf[tid-1] : make_float2(0.f, 0.f);
  __syncthreads();

  // ---- per-element theta, contributions c = fw*cos(theta) ----
  float thP = thBase.x, thT = thBase.y;
  float cP[CHUNK], cT[CHUNK];
  float2 xsum = make_float2(0.f, 0.f);
  #pragma unroll
  for (int k = 0; k < CHUNK; ++k) {
    cP[k] = fwP[k] * cosf(thP);
    cT[k] = fwT[k] * cosf(thT);
    thP += dthP[k]; thT += dthT[k];     // theta read before update
    xsum.x += cP[k]; xsum.y += cT[k];
  }

  // ---- scan 2: x = inclusive prefix of c ----
  sbuf[tid] = xsum;
  __syncthreads();
  #pragma unroll
  for (int off = 1; off < NTHREADS; off <<= 1) {
    float2 a = make_float2(0.f, 0.f);
    if (tid >= off) a = sbuf[tid - off];
    __syncthreads();
    if (tid >= off) { float2 c = sbuf[tid]; c.x += a.x; c.y += a.y; sbuf[tid] = c; }
    __syncthreads();
  }
  float2 xBase = (tid > 0) ? sbuf[tid-1] : make_float2(0.f, 0.f);
  __syncthreads();

  // ---- loss terms for this chunk ----
  float xP = xBase.x, xT = xBase.y, acc = 0.f;
  #pragma unroll
  for (int k = 0; k < CHUNK; ++k) {
    xP += cP[k]; xT += cT[k];
    float dx = xP - xT;
    acc += sqrtf(2.0f * dx * dx + 1e-12f);   // dx*dx + dx*dx + eps (faithful)
  }

  // ---- block reduce ----
  rbuf[tid] = acc;
  __syncthreads();
  #pragma unroll
  for (int off = NTHREADS/2; off > 0; off >>= 1) {
    if (tid < off) rbuf[tid] += rbuf[tid + off];
    __syncthreads();
  }
  if (tid == 0) partial[b] = rbuf[0];
}

__global__ __launch_bounds__(256) void path_loss_reduce(
    const float* __restrict__ partial, float* __restrict__ out)
{
  __shared__ double rb[256];
  double s = 0.0;
  for (int i = threadIdx.x; i < B_DIM; i += 256) s += (double)partial[i];
  rb[threadIdx.x] = s;
  __syncthreads();
  for (int off = 128; off > 0; off >>= 1) {
    if (threadIdx.x < off) rb[threadIdx.x] += rb[threadIdx.x + off];
    __syncthreads();
  }
  if (threadIdx.x == 0) {
    // t=0 column: dx==0 -> sqrt(1e-12) = 1e-6 per row
    double total = rb[0] + (double)B_DIM * 1e-6;
    out[0] = (float)(total / ((double)B_DIM * (double)(T_DIM + 1)));
  }
}

extern "C" void kernel_launch(void* const* d_in, const int* in_sizes, int n_in,
                              void* d_out, int out_size, void* d_ws, size_t ws_size,
                              hipStream_t stream) {
  const float* outs   = (const float*)d_in[0];
  const int*   labels = (const int*)d_in[1];
  float* partial = (float*)d_ws;
  float* out     = (float*)d_out;

  path_loss_rows<<<B_DIM, NTHREADS, 0, stream>>>(outs, labels, partial);
  path_loss_reduce<<<1, 256, 0, stream>>>(partial, out);
}

// Round 2
// 19.148 us; speedup vs baseline: 1.2196x; 1.2196x over previous
//
#include <hip/hip_runtime.h>
#include <math.h>

#define NT 512
#define WAVES (NT / 64)
#define T_DIM 2048
#define B_DIM 1024
#define CHUNK (T_DIM / NT)   // 4 timesteps per thread

// Wave64 inclusive scan of a float2 (component-wise).
__device__ inline float2 wave_incl_scan(float2 v, int lane) {
  #pragma unroll
  for (int d = 1; d < 64; d <<= 1) {
    float ax = __shfl_up(v.x, d, 64);
    float ay = __shfl_up(v.y, d, 64);
    if (lane >= d) { v.x += ax; v.y += ay; }
  }
  return v;
}

// One block per batch row. Each thread owns CHUNK=4 consecutive timesteps.
// Fused (predicted, true) scans: theta (exclusive), x (inclusive).
__global__ __launch_bounds__(NT) void path_loss_rows(
    const float* __restrict__ outs,
    const int*   __restrict__ labels,
    float*       __restrict__ partial)
{
  __shared__ float2 wsum[WAVES];
  __shared__ float2 wsum2[WAVES];
  __shared__ float  rsum[WAVES];

  const int tid  = threadIdx.x;
  const int lane = tid & 63;
  const int wid  = tid >> 6;
  const int b    = blockIdx.x;
  const int t0   = tid * CHUNK;

  const float* rowO = outs   + (size_t)b * T_DIM * 5;
  const int*   rowL = labels + (size_t)b * T_DIM;

  // ---- load CHUNK*5 = 20 floats (5x float4, base tid*80B is 16B-aligned) ----
  float vals[20];
  const float4* vp = reinterpret_cast<const float4*>(rowO + (size_t)t0 * 5);
  #pragma unroll
  for (int j = 0; j < 5; ++j) {
    float4 v = vp[j];
    vals[4*j+0] = v.x; vals[4*j+1] = v.y; vals[4*j+2] = v.z; vals[4*j+3] = v.w;
  }
  // ---- 4 labels: one int4 (16B-aligned) ----
  int lbl[CHUNK];
  {
    int4 l0 = reinterpret_cast<const int4*>(rowL + t0)[0];
    lbl[0] = l0.x; lbl[1] = l0.y; lbl[2] = l0.z; lbl[3] = l0.w;
  }

  const float WT = 1.0f / (1.0f + 1e-6f);
  float dthP[CHUNK], fwP[CHUNK], dthT[CHUNK], fwT[CHUNK];
  #pragma unroll
  for (int k = 0; k < CHUNK; ++k) {
    float o0 = vals[5*k+0], o1 = vals[5*k+1], o2 = vals[5*k+2],
          o3 = vals[5*k+3], o4 = vals[5*k+4];
    // first-occurrence argmax (strict >) matches jnp.argmax
    float m = o0; int am = 0;
    if (o1 > m) { m = o1; am = 1; }
    if (o2 > m) { m = o2; am = 2; }
    if (o3 > m) { m = o3; am = 3; }
    if (o4 > m) { m = o4; am = 4; }
    float sum = __expf(o0-m) + __expf(o1-m) + __expf(o2-m)
              + __expf(o3-m) + __expf(o4-m);
    float s = 1.0f / sum;            // softmax value at the argmax class
    float w = s / (s + 1e-6f);
    float sgn = (am==1 || am==3) ? 1.0f : ((am==2 || am==4) ? -1.0f : 0.0f);
    fwP[k]  = (am==0 || am==3 || am==4) ? w : 0.0f;
    dthP[k] = 0.15f * sgn * w;

    int l = lbl[k];
    float sgt = (l==1 || l==3) ? 1.0f : ((l==2 || l==4) ? -1.0f : 0.0f);
    fwT[k]  = (l==0 || l==3 || l==4) ? WT : 0.0f;
    dthT[k] = 0.15f * sgt * WT;
  }

  // ================= scan 1: exclusive prefix of dth ====================
  float2 csum = make_float2(0.f, 0.f);
  #pragma unroll
  for (int k = 0; k < CHUNK; ++k) { csum.x += dthP[k]; csum.y += dthT[k]; }

  float2 incl = wave_incl_scan(csum, lane);
  if (lane == 63) wsum[wid] = incl;
  __syncthreads();                                   // barrier 1
  float2 base = make_float2(0.f, 0.f);
  #pragma unroll
  for (int w = 0; w < WAVES; ++w) {
    float2 t = wsum[w];
    if (w < wid) { base.x += t.x; base.y += t.y; }
  }
  float ex = __shfl_up(incl.x, 1, 64);
  float ey = __shfl_up(incl.y, 1, 64);
  float thP = base.x + ((lane == 0) ? 0.f : ex);
  float thT = base.y + ((lane == 0) ? 0.f : ey);

  // ---- per-element theta; contributions c = fw * cos(theta) ----
  float cP[CHUNK], cT[CHUNK];
  float2 xsum = make_float2(0.f, 0.f);
  #pragma unroll
  for (int k = 0; k < CHUNK; ++k) {
    cP[k] = fwP[k] * __cosf(thP);      // v_cos_f32: |theta| <= 307 rad ~ 49 rev, in range
    cT[k] = fwT[k] * __cosf(thT);
    thP += dthP[k]; thT += dthT[k];    // theta read before update
    xsum.x += cP[k]; xsum.y += cT[k];
  }

  // ================= scan 2: inclusive prefix of c ======================
  float2 incl2 = wave_incl_scan(xsum, lane);
  __syncthreads();                                   // barrier 2 (wsum reads done)
  if (lane == 63) wsum2[wid] = incl2;
  __syncthreads();                                   // barrier 3
  float2 base2 = make_float2(0.f, 0.f);
  #pragma unroll
  for (int w = 0; w < WAVES; ++w) {
    float2 t = wsum2[w];
    if (w < wid) { base2.x += t.x; base2.y += t.y; }
  }
  float ex2 = __shfl_up(incl2.x, 1, 64);
  float ey2 = __shfl_up(incl2.y, 1, 64);
  float xP = base2.x + ((lane == 0) ? 0.f : ex2);
  float xT = base2.y + ((lane == 0) ? 0.f : ey2);

  // ---- loss terms ----
  float acc = 0.f;
  #pragma unroll
  for (int k = 0; k < CHUNK; ++k) {
    xP += cP[k]; xT += cT[k];
    float dx = xP - xT;
    acc += sqrtf(2.0f * dx * dx + 1e-12f);   // dx*dx + dx*dx + eps (faithful)
  }

  // ---- block reduce: wave shuffle + 8-entry LDS combine ----
  #pragma unroll
  for (int d = 32; d > 0; d >>= 1) acc += __shfl_down(acc, d, 64);
  if (lane == 0) rsum[wid] = acc;
  __syncthreads();                                   // barrier 4
  if (tid == 0) {
    float s = 0.f;
    #pragma unroll
    for (int w = 0; w < WAVES; ++w) s += rsum[w];
    partial[b] = s;
  }
}

__global__ __launch_bounds__(1024) void path_loss_reduce(
    const float* __restrict__ partial, float* __restrict__ out)
{
  __shared__ double rb[16];
  const int tid = threadIdx.x, lane = tid & 63, wid = tid >> 6;
  double s = (double)partial[tid];
  #pragma unroll
  for (int d = 32; d > 0; d >>= 1) s += __shfl_down(s, d, 64);
  if (lane == 0) rb[wid] = s;
  __syncthreads();
  if (tid == 0) {
    double tot = 0.0;
    #pragma unroll
    for (int w = 0; w < 16; ++w) tot += rb[w];
    tot += (double)B_DIM * 1e-6;    // t=0 column: sqrt(1e-12) per row
    out[0] = (float)(tot / ((double)B_DIM * (double)(T_DIM + 1)));
  }
}

extern "C" void kernel_launch(void* const* d_in, const int* in_sizes, int n_in,
                              void* d_out, int out_size, void* d_ws, size_t ws_size,
                              hipStream_t stream) {
  const float* outs   = (const float*)d_in[0];
  const int*   labels = (const int*)d_in[1];
  float* partial = (float*)d_ws;
  float* out     = (float*)d_out;

  path_loss_rows<<<B_DIM, NT, 0, stream>>>(outs, labels, partial);
  path_loss_reduce<<<1, 1024, 0, stream>>>(partial, out);
}